// Round 13
// baseline (2762.504 us; speedup 1.0000x reference)
//
#include <hip/hip_runtime.h>
#include <cstdint>
#include <cstddef>

#define S_   1024
#define D_   1024
#define H_   8
#define DH_  128
#define IT_  28
#define V_   50257
#define B_   2
#define ROWS 2048
#define EPS_ 1.1920929e-07f

typedef unsigned short u16;
typedef __attribute__((ext_vector_type(8))) short s8v;    // 8 bf16 in 4 VGPRs
typedef __attribute__((ext_vector_type(4))) float f4v;    // MFMA accumulator

#define VMCNT0 asm volatile("s_waitcnt vmcnt(0)" ::: "memory")
#define LGKM0  asm volatile("s_waitcnt lgkmcnt(0)" ::: "memory")
#define RBAR   do { __builtin_amdgcn_s_barrier(); asm volatile("" ::: "memory"); } while (0)

static __device__ __forceinline__ void gload16(const void* g, void* l) {
  __builtin_amdgcn_global_load_lds((__attribute__((address_space(1))) void*)(g),
                                   (__attribute__((address_space(3))) void*)(l), 16, 0, 0);
}

static __device__ __forceinline__ u16 f2bf(float f) {
  union { float f; uint32_t u; } v; v.f = f;
  return (u16)((v.u + 0x7FFFu + ((v.u >> 16) & 1u)) >> 16);
}

static __device__ __forceinline__ float wave_sum(float v) {
#pragma unroll
  for (int o = 32; o > 0; o >>= 1) v += __shfl_xor(v, o, 64);
  return v;
}

// chunk tables: 40 (it, chunk) pairs per bh, longest chunks first
__device__ __constant__ int IT_TAB[40] = {
  15,15,15,15, 14,14,14, 13,13,13, 12,12,12, 11,11,11,
  10,10, 9,9, 8,8, 7,7, 6, 5, 4, 3,
  14,10,6,2, 13,9,5,1, 12,8,4,0};
__device__ __constant__ int CH_TAB[40] = {
  0,1,2,3, 0,1,2, 0,1,2, 0,1,2, 0,1,2,
  0,1, 0,1, 0,1, 0,1, 0, 0, 0, 0,
  3,2,1,0, 3,2,1,0, 3,2,1,0};

// ---------------- embedding gather ----------------
__global__ __launch_bounds__(256) void k_embed(const int* __restrict__ tok,
                                               const float* __restrict__ emb,
                                               float* __restrict__ x) {
  const int row = blockIdx.x;
  const int t = tok[row];
  ((float4*)(x + (size_t)row * D_))[threadIdx.x] =
      ((const float4*)(emb + (size_t)t * D_))[threadIdx.x];
}

// ---------------- fp32 -> bf16 convert ----------------
__global__ __launch_bounds__(256) void k_cvt(const float* __restrict__ w,
                                             u16* __restrict__ o, int n4) {
  const int idx = blockIdx.x * 256 + threadIdx.x;
  if (idx < n4) {
    const float4 f = ((const float4*)w)[idx];
    ushort4 u;
    u.x = f2bf(f.x); u.y = f2bf(f.y); u.z = f2bf(f.z); u.w = f2bf(f.w);
    ((ushort4*)o)[idx] = u;
  }
}

// ---------------- fused RMSNorm (*nw) [*gamma + beta] -> bf16 ----------------
__global__ __launch_bounds__(256) void k_rmsnorm(const float* __restrict__ x,
                                                 const float* __restrict__ nw,
                                                 const float* __restrict__ g,
                                                 const float* __restrict__ bb,
                                                 u16* __restrict__ h) {
  const int row = blockIdx.x;
  const int tid = threadIdx.x;
  const float4 xv = ((const float4*)(x + (size_t)row * D_))[tid];
  float ss = xv.x*xv.x + xv.y*xv.y + xv.z*xv.z + xv.w*xv.w;
  ss = wave_sum(ss);
  __shared__ float red[4];
  const int lane = tid & 63, wid = tid >> 6;
  if (lane == 0) red[wid] = ss;
  __syncthreads();
  const float tot = red[0] + red[1] + red[2] + red[3];
  const float r = rsqrtf(tot * (1.0f / (float)D_) + EPS_);
  const float4 wv = ((const float4*)nw)[tid];
  float o[4];
  o[0] = xv.x * r * wv.x; o[1] = xv.y * r * wv.y;
  o[2] = xv.z * r * wv.z; o[3] = xv.w * r * wv.w;
  if (g) {
    const float4 gv = ((const float4*)g)[tid];
    const float4 bv = ((const float4*)bb)[tid];
    o[0] = o[0]*gv.x + bv.x; o[1] = o[1]*gv.y + bv.y;
    o[2] = o[2]*gv.z + bv.z; o[3] = o[3]*gv.w + bv.w;
  }
  ushort4 u;
  u.x = f2bf(o[0]); u.y = f2bf(o[1]); u.z = f2bf(o[2]); u.w = f2bf(o[3]);
  ((ushort4*)(h + (size_t)row * D_))[tid] = u;
}

// T2 slot swizzle (all GEMMs): element (row, ks16B) lives at LDS 16B-slot
// row*4 + (ks ^ ((row>>1)&3)).  Staging: pre-swizzled GLOBAL source (within-quad
// permutation of the same 64B line — coalescing intact), LDS dest lane-linear.
// Read: slot = l4 ^ ((l15>>1)&3) -> conflict-free (verified: 25.8M -> 0).
//
// XCD work-clustering: wk=(bid&7)*per+(bid>>3), i-tile fastest -> all i-readers
// of a B-panel on ONE XCD (lm_head FETCH 420->202 MB verified; in-loop -35 us).

// ---------------- in-loop bf16 MFMA NT GEMM (2-phase dbuf + T2 + XCD-cluster) --------
// C[i][j] += alpha * sum_k A[i][k]*B[j][k].  BM=128 BN=64 BK=32, 4 waves (2x2).
// 1-D grid 256 = 8 XCD x (16 i x 2 j-panels).
__global__ __launch_bounds__(256) void k_gemm2(const u16* __restrict__ A, int lda,
                                               const u16* __restrict__ Bm, int ldb,
                                               float* __restrict__ C, int ldc,
                                               int K,
                                               const float* __restrict__ alphap, int aidx) {
  __shared__ u16 As0[128 * 32], As1[128 * 32];
  __shared__ u16 Bs0[64 * 32], Bs1[64 * 32];
  const int wk = (blockIdx.x & 7) * (gridDim.x >> 3) + (blockIdx.x >> 3);
  const int i0 = (wk & 15) * 128;
  const int j0 = (wk >> 4) * 64;
  const int tid = threadIdx.x;
  const int lane = tid & 63, w = tid >> 6;
  const int wr = w >> 1, wc = w & 1;
  const int l15 = lane & 15, l4 = lane >> 4;
  const int ar = tid >> 2;
  const int ak = (((tid & 3) ^ ((ar >> 1) & 3)) << 3);   // swizzled global col offset
  const int sw = (l15 >> 1) & 3;                          // read-side slot XOR

  f4v acc[4][2];
#pragma unroll
  for (int m = 0; m < 4; ++m)
#pragma unroll
    for (int n = 0; n < 2; ++n) acc[m][n] = (f4v)0.0f;

  auto STAGE = [&](u16* AsB, u16* BsB, int k0) {
    gload16(A + (size_t)(i0 + ar) * lda + k0 + ak, AsB + (size_t)tid * 8);
    gload16(A + (size_t)(i0 + ar + 64) * lda + k0 + ak, AsB + ((size_t)tid + 256) * 8);
    gload16(Bm + (size_t)(j0 + ar) * ldb + k0 + ak, BsB + (size_t)tid * 8);
  };
  auto COMP = [&](const u16* AsB, const u16* BsB) {
    s8v a[4], b[2];
#pragma unroll
    for (int m = 0; m < 4; ++m)
      a[m] = *(const s8v*)&AsB[(wr * 64 + m * 16 + l15) * 32 + ((l4 ^ sw) << 3)];
#pragma unroll
    for (int n = 0; n < 2; ++n)
      b[n] = *(const s8v*)&BsB[(wc * 32 + n * 16 + l15) * 32 + ((l4 ^ sw) << 3)];
#pragma unroll
    for (int m = 0; m < 4; ++m)
#pragma unroll
      for (int n = 0; n < 2; ++n)
        acc[m][n] = __builtin_amdgcn_mfma_f32_16x16x32_bf16(a[m], b[n], acc[m][n], 0, 0, 0);
  };

  STAGE(As0, Bs0, 0);
  VMCNT0;
  RBAR;
  for (int k0 = 0; k0 < K; k0 += 64) {
    STAGE(As1, Bs1, k0 + 32);
    COMP(As0, Bs0);
    VMCNT0;
    RBAR;
    if (k0 + 64 < K) STAGE(As0, Bs0, k0 + 64);
    COMP(As1, Bs1);
    VMCNT0;
    RBAR;
  }

  const float alpha = alphap[aidx];
#pragma unroll
  for (int m = 0; m < 4; ++m) {
#pragma unroll
    for (int n = 0; n < 2; ++n) {
      const int i = i0 + wr * 64 + m * 16 + l4 * 4;
      const int j = j0 + wc * 32 + n * 16 + l15;
      const f4v v = acc[m][n];
#pragma unroll
      for (int r = 0; r < 4; ++r) C[(size_t)(i + r) * ldc + j] += alpha * v[r];
    }
  }
}

// ---------------- lm_head GEMM (3-buf counted pipeline + T2 + XCD-clustered work) ----------------
// C[i][j] = sum_k A[i][k]*B[j][k], store f32 guarded j<N.  BM=128 BN=128 BK=32.
__global__ __launch_bounds__(256) void k_gemm_lm(const u16* __restrict__ A, int lda,
                                                 const u16* __restrict__ Bm, int ldb,
                                                 float* __restrict__ C, int ldc,
                                                 int N, int K) {
  __shared__ u16 As0[128 * 32], As1[128 * 32], As2[128 * 32];
  __shared__ u16 Bs0[128 * 32], Bs1[128 * 32], Bs2[128 * 32];
  const int per = gridDim.x >> 3;                 // blocks per XCD (6288/8 = 786)
  const int wk = (blockIdx.x & 7) * per + (blockIdx.x >> 3);
  const int i0 = (wk & 15) * 128;                 // i-tile (16 of them, fastest)
  const int j0 = (wk >> 4) * 128;                 // j-panel
  const int tid = threadIdx.x;
  const int lane = tid & 63, w = tid >> 6;
  const int wr = w >> 1, wc = w & 1;
  const int l15 = lane & 15, l4 = lane >> 4;
  const int ar = tid >> 2;
  const int ak = (((tid & 3) ^ ((ar >> 1) & 3)) << 3);
  const int sw = (l15 >> 1) & 3;
  int bj0 = j0 + ar;      if (bj0 > N - 1) bj0 = N - 1;
  int bj1 = j0 + ar + 64; if (bj1 > N - 1) bj1 = N - 1;

  f4v acc[4][4];
#pragma unroll
  for (int m = 0; m < 4; ++m)
#pragma unroll
    for (int n = 0; n < 4; ++n) acc[m][n] = (f4v)0.0f;

  auto STAGE = [&](u16* AsB, u16* BsB, int k0) {
    gload16(A + (size_t)(i0 + ar) * lda + k0 + ak, AsB + (size_t)tid * 8);
    gload16(A + (size_t)(i0 + ar + 64) * lda + k0 + ak, AsB + ((size_t)tid + 256) * 8);
    gload16(Bm + (size_t)bj0 * ldb + k0 + ak, BsB + (size_t)tid * 8);
    gload16(Bm + (size_t)bj1 * ldb + k0 + ak, BsB + ((size_t)tid + 256) * 8);
  };
  auto COMP = [&](const u16* AsB, const u16* BsB) {
    s8v a[4], b[4];
#pragma unroll
    for (int m = 0; m < 4; ++m)
      a[m] = *(const s8v*)&AsB[(wr * 64 + m * 16 + l15) * 32 + ((l4 ^ sw) << 3)];
#pragma unroll
    for (int n = 0; n < 4; ++n)
      b[n] = *(const s8v*)&BsB[(wc * 64 + n * 16 + l15) * 32 + ((l4 ^ sw) << 3)];
#pragma unroll
    for (int m = 0; m < 4; ++m)
#pragma unroll
      for (int n = 0; n < 4; ++n)
        acc[m][n] = __builtin_amdgcn_mfma_f32_16x16x32_bf16(a[m], b[n], acc[m][n], 0, 0, 0);
  };
  auto WAIT = [&](int ahead) {
    if (ahead >= 2)      asm volatile("s_waitcnt vmcnt(8)" ::: "memory");
    else if (ahead == 1) asm volatile("s_waitcnt vmcnt(4)" ::: "memory");
    else                 VMCNT0;
  };

  const int nk = K >> 5;  // K multiple of 32, nk >= 3
  STAGE(As0, Bs0, 0);
  STAGE(As1, Bs1, 32);
  STAGE(As2, Bs2, 64);
  for (int i = 0; i < nk; ++i) {
    u16 *Asb, *Bsb;
    const int m3 = i % 3;
    if (m3 == 0) { Asb = As0; Bsb = Bs0; }
    else if (m3 == 1) { Asb = As1; Bsb = Bs1; }
    else { Asb = As2; Bsb = Bs2; }
    const int rem = nk - 1 - i;
    WAIT(rem < 2 ? rem : 2);
    RBAR;
    COMP(Asb, Bsb);
    RBAR;
    if (i + 3 < nk) STAGE(Asb, Bsb, (i + 3) << 5);
  }

#pragma unroll
  for (int m = 0; m < 4; ++m) {
#pragma unroll
    for (int n = 0; n < 4; ++n) {
      const int i = i0 + wr * 64 + m * 16 + l4 * 4;
      const int j = j0 + wc * 64 + n * 16 + l15;
      const f4v v = acc[m][n];
      if (j < N) {
#pragma unroll
        for (int r = 0; r < 4; ++r) C[(size_t)(i + r) * ldc + j] = v[r];
      }
    }
  }
}

// ---------------- batched QKV GEMM (2-phase dbuf + T2 + XCD-cluster) ----------------
// A=hb[2048][1024], B=Wcat[3072][1024]; BM=128 BN=64 BK=32.
// 1-D grid 768 = 8 XCD x (16 i x 6 j-panels).
__global__ __launch_bounds__(256) void k_gemm_qkv(const u16* __restrict__ A,
                                                  const u16* __restrict__ Wcat,
                                                  u16* __restrict__ kb,
                                                  u16* __restrict__ vt,
                                                  float* __restrict__ fb) {
  __shared__ u16 As0[128 * 32], As1[128 * 32];
  __shared__ u16 Bs0[64 * 32], Bs1[64 * 32];
  const int wk = (blockIdx.x & 7) * (gridDim.x >> 3) + (blockIdx.x >> 3);
  const int i0 = (wk & 15) * 128;
  const int j0 = (wk >> 4) * 64;
  const int tid = threadIdx.x;
  const int lane = tid & 63, w = tid >> 6;
  const int wr = w >> 1, wc = w & 1;
  const int l15 = lane & 15, l4 = lane >> 4;
  const int ar = tid >> 2;
  const int ak = (((tid & 3) ^ ((ar >> 1) & 3)) << 3);
  const int sw = (l15 >> 1) & 3;

  f4v acc[4][2];
#pragma unroll
  for (int m = 0; m < 4; ++m)
#pragma unroll
    for (int n = 0; n < 2; ++n) acc[m][n] = (f4v)0.0f;

  auto STAGE = [&](u16* AsB, u16* BsB, int k0) {
    gload16(A + (size_t)(i0 + ar) * D_ + k0 + ak, AsB + (size_t)tid * 8);
    gload16(A + (size_t)(i0 + ar + 64) * D_ + k0 + ak, AsB + ((size_t)tid + 256) * 8);
    gload16(Wcat + (size_t)(j0 + ar) * D_ + k0 + ak, BsB + (size_t)tid * 8);
  };
  auto COMP = [&](const u16* AsB, const u16* BsB) {
    s8v a[4], b[2];
#pragma unroll
    for (int m = 0; m < 4; ++m)
      a[m] = *(const s8v*)&AsB[(wr * 64 + m * 16 + l15) * 32 + ((l4 ^ sw) << 3)];
#pragma unroll
    for (int n = 0; n < 2; ++n)
      b[n] = *(const s8v*)&BsB[(wc * 32 + n * 16 + l15) * 32 + ((l4 ^ sw) << 3)];
#pragma unroll
    for (int m = 0; m < 4; ++m)
#pragma unroll
      for (int n = 0; n < 2; ++n)
        acc[m][n] = __builtin_amdgcn_mfma_f32_16x16x32_bf16(a[m], b[n], acc[m][n], 0, 0, 0);
  };

  STAGE(As0, Bs0, 0);
  VMCNT0;
  RBAR;
  for (int k0 = 0; k0 < D_; k0 += 64) {
    STAGE(As1, Bs1, k0 + 32);
    COMP(As0, Bs0);
    VMCNT0;
    RBAR;
    if (k0 + 64 < D_) STAGE(As0, Bs0, k0 + 64);
    COMP(As1, Bs1);
    VMCNT0;
    RBAR;
  }

#pragma unroll
  for (int m = 0; m < 4; ++m) {
#pragma unroll
    for (int n = 0; n < 2; ++n) {
      const int i = i0 + wr * 64 + m * 16 + l4 * 4;
      const int j = j0 + wc * 32 + n * 16 + l15;
      const int sel = j >> 10, jl = j & 1023;
      const f4v v = acc[m][n];
      if (sel == 0) {
#pragma unroll
        for (int r = 0; r < 4; ++r) kb[(size_t)(i + r) * D_ + jl] = f2bf(v[r]);
      } else if (sel == 1) {
        ushort4 p;
        p.x = f2bf(v[0]); p.y = f2bf(v[1]); p.z = f2bf(v[2]); p.w = f2bf(v[3]);
        *(ushort4*)&vt[((size_t)(i >> 10) * D_ + jl) * S_ + (i & 1023)] = p;
      } else {
#pragma unroll
        for (int r = 0; r < 4; ++r) fb[(size_t)(i + r) * D_ + jl] = v[r];
      }
    }
  }
}

// ---------------- flash attention partial: one (it, j-chunk<=4 tiles) per block ----------------
// Round 13: double-buffered K/V (T14 early-issue) + ONE barrier per KV-tile.
// Per tile jt: issue stage(jt+1 -> buf^1) FIRST (latency hides under QK+softmax+PV),
// then QK (Kj[cur]) -> softmax -> P->LDS (per-wave, lgkmcnt-only ordering) -> PV
// (Vj[cur]) -> vmcnt(0) [next tile landed] -> barrier -> cur^=1.
// Overwrite safety: each wave's reads of buf b complete before its MFMAs, which
// precede the end-of-tile barrier; b is only re-staged one full tile later.
__global__ __launch_bounds__(256) void k_attn_part(const u16* __restrict__ kb,
                                                   const u16* __restrict__ vt,
                                                   float* __restrict__ po,
                                                   float* __restrict__ pml,
                                                   float scale) {
  const int it = IT_TAB[blockIdx.x], ch = CH_TAB[blockIdx.x];
  const int z = blockIdx.y;
  const int b = z >> 3, h = z & 7;
  const u16* Kbh = kb + (size_t)b * S_ * D_ + h * DH_;      // row s, stride D_
  const u16* Vth = vt + ((size_t)b * D_ + h * DH_) * S_;    // row d, stride S_
  const int i0 = it * 64;
  const int jt0 = ch * 4;
  const int jtend = min(jt0 + 4, it + 1);
  __shared__ u16 Kj[2][64 * 128];   // [buf][j-row][k] swizzled
  __shared__ u16 Vj[2][128 * 64];   // [buf][d][j] swizzled
  __shared__ u16 Pl[4][16 * 64];    // per-wave P, swizzled
  const int tid = threadIdx.x;
  const int lane = tid & 63, w = tid >> 6;
  const int l15 = lane & 15, l4 = lane >> 4;

  s8v ka[4];
#pragma unroll
  for (int ks = 0; ks < 4; ++ks)
    ka[ks] = *(const s8v*)(Kbh + (size_t)(i0 + w * 16 + l15) * D_ + ks * 32 + l4 * 8);

  f4v acc_o[8];
#pragma unroll
  for (int n = 0; n < 8; ++n) acc_o[n] = (f4v)0.0f;
  float mrow[4], lrow[4];
#pragma unroll
  for (int r = 0; r < 4; ++r) { mrow[r] = -3.0e38f; lrow[r] = 0.f; }

  const int krow = tid >> 4, koff = (tid & 15) * 8;  // Kj staging
  const int vrow = tid >> 3, voff = (tid & 7) * 8;   // Vj staging

  auto stageKV = [&](int j0g, int bi) {
    u16* Kd = Kj[bi];
    u16* Vd = Vj[bi];
#pragma unroll
    for (int p = 0; p < 4; ++p) {
      const int row = p * 16 + krow;
      gload16(Kbh + (size_t)(j0g + row) * D_ + (koff ^ ((row & 7) << 3)),
              Kd + (size_t)(p * 256 + tid) * 8);
    }
#pragma unroll
    for (int p = 0; p < 4; ++p) {
      const int row = p * 32 + vrow;
      gload16(Vth + (size_t)row * S_ + j0g + (voff ^ ((row & 7) << 3)),
              Vd + (size_t)(p * 256 + tid) * 8);
    }
  };

  // prologue: tile jt0 -> buf0
  stageKV(jt0 * 64, 0);
  VMCNT0;
  RBAR;

  int cur = 0;
  for (int jt = jt0; jt < jtend; ++jt) {
    const int j0 = jt * 64;
    // issue next tile's staging first — latency hides under this tile's compute
    if (jt + 1 < jtend) stageKV((jt + 1) * 64, cur ^ 1);
    const u16* Kc = Kj[cur];
    const u16* Vc = Vj[cur];

    // S = K_i . K_j^T
    f4v s[4];
#pragma unroll
    for (int n = 0; n < 4; ++n) s[n] = (f4v)0.0f;
    __builtin_amdgcn_s_setprio(1);
#pragma unroll
    for (int ks = 0; ks < 4; ++ks) {
#pragma unroll
      for (int n = 0; n < 4; ++n) {
        const int row = n * 16 + l15;
        const s8v kf = *(const s8v*)&Kc[row * 128 + ((ks * 32 + l4 * 8) ^ ((row & 7) << 3))];
        s[n] = __builtin_amdgcn_mfma_f32_16x16x32_bf16(ka[ks], kf, s[n], 0, 0, 0);
      }
    }
    __builtin_amdgcn_s_setprio(0);

    // online softmax of logits = -scale*S, causal
    float pv[4][4], tmax[4];
#pragma unroll
    for (int r = 0; r < 4; ++r) tmax[r] = -3.0e38f;
#pragma unroll
    for (int n = 0; n < 4; ++n) {
      const int j = j0 + n * 16 + l15;
#pragma unroll
      for (int r = 0; r < 4; ++r) {
        const int i = i0 + w * 16 + l4 * 4 + r;
        const float lg = (j <= i) ? (-scale * s[n][r]) : -3.0e38f;
        pv[n][r] = lg;
        tmax[r] = fmaxf(tmax[r], lg);
      }
    }
#pragma unroll
    for (int r = 0; r < 4; ++r) {
#pragma unroll
      for (int o = 8; o > 0; o >>= 1) tmax[r] = fmaxf(tmax[r], __shfl_xor(tmax[r], o, 64));
    }
    float es[4];
#pragma unroll
    for (int r = 0; r < 4; ++r) {
      const float mn = fmaxf(mrow[r], tmax[r]);
      es[r] = __expf(mrow[r] - mn);
      mrow[r] = mn;
    }
    float psum[4] = {0.f, 0.f, 0.f, 0.f};
#pragma unroll
    for (int n = 0; n < 4; ++n) {
#pragma unroll
      for (int r = 0; r < 4; ++r) {
        const float p = __expf(pv[n][r] - mrow[r]);
        pv[n][r] = p;
        psum[r] += p;
      }
    }
#pragma unroll
    for (int r = 0; r < 4; ++r) {
#pragma unroll
      for (int o = 8; o > 0; o >>= 1) psum[r] += __shfl_xor(psum[r], o, 64);
      lrow[r] = lrow[r] * es[r] + psum[r];
    }
#pragma unroll
    for (int n = 0; n < 8; ++n) {
      f4v t = acc_o[n];
      t[0] *= es[0]; t[1] *= es[1]; t[2] *= es[2]; t[3] *= es[3];
      acc_o[n] = t;
    }

    // P -> per-wave LDS (swizzled); per-wave private, so lgkmcnt ordering suffices
    u16* P = Pl[w];
#pragma unroll
    for (int n = 0; n < 4; ++n) {
#pragma unroll
      for (int r = 0; r < 4; ++r) {
        const int row = l4 * 4 + r;
        P[row * 64 + ((n * 16 + l15) ^ ((row & 7) << 3))] = f2bf(pv[n][r]);
      }
    }
    LGKM0;
    __builtin_amdgcn_sched_barrier(0);
    s8v pa[2];
#pragma unroll
    for (int kp = 0; kp < 2; ++kp)
      pa[kp] = *(const s8v*)&P[l15 * 64 + ((kp * 32 + l4 * 8) ^ ((l15 & 7) << 3))];

    // O += P . V
    __builtin_amdgcn_s_setprio(1);
#pragma unroll
    for (int kp = 0; kp < 2; ++kp) {
#pragma unroll
      for (int n = 0; n < 8; ++n) {
        const int d = n * 16 + l15;
        const s8v vf = *(const s8v*)&Vc[d * 64 + ((kp * 32 + l4 * 8) ^ ((d & 7) << 3))];
        acc_o[n] = __builtin_amdgcn_mfma_f32_16x16x32_bf16(pa[kp], vf, acc_o[n], 0, 0, 0);
      }
    }
    __builtin_amdgcn_s_setprio(0);

    VMCNT0;   // next tile's staging landed (latency was covered by QK/softmax/PV)
    RBAR;     // all waves done reading buf[cur] + all staging visible
    cur ^= 1;
  }

  // partial store: O (unnormalized), m, l
  const int slot = (z * 16 + it) * 4 + ch;
  float* O = po + (size_t)slot * (64 * 128);
#pragma unroll
  for (int n = 0; n < 8; ++n) {
#pragma unroll
    for (int r = 0; r < 4; ++r)
      O[(w * 16 + l4 * 4 + r) * 128 + n * 16 + l15] = acc_o[n][r];
  }
  if (l15 == 0) {
#pragma unroll
    for (int r = 0; r < 4; ++r) {
      const int row = w * 16 + l4 * 4 + r;
      pml[(size_t)slot * 128 + row] = mrow[r];
      pml[(size_t)slot * 128 + 64 + row] = lrow[r];
    }
  }
}

// ---------------- merge partial attention chunks; fbh = bf16(fb + O/l) ----------------
__global__ __launch_bounds__(256) void k_attn_merge(const float* __restrict__ po,
                                                    const float* __restrict__ pml,
                                                    const float* __restrict__ fb,
                                                    u16* __restrict__ fbh) {
  const int it = blockIdx.x, z = blockIdx.y;
  const int b = z >> 3, h = z & 7;
  const int nch = (it >> 2) + 1;
  const int row = threadIdx.x >> 2;            // 0..63
  const int cseg = (threadIdx.x & 3) * 32;     // col base within 128
  const int base = (z * 16 + it) * 4;

  float ms = -3.0e38f, mv[4], lv[4];
#pragma unroll
  for (int c = 0; c < 4; ++c)
    if (c < nch) {
      mv[c] = pml[(size_t)(base + c) * 128 + row];
      lv[c] = pml[(size_t)(base + c) * 128 + 64 + row];
      ms = fmaxf(ms, mv[c]);
    }
  float ls = 0.f, fac[4];
#pragma unroll
  for (int c = 0; c < 4; ++c)
    if (c < nch) { fac[c] = __expf(mv[c] - ms); ls += lv[c] * fac[c]; }
  const float inv = 1.0f / ls;

  float4 o[8];
#pragma unroll
  for (int q = 0; q < 8; ++q) o[q] = make_float4(0.f, 0.f, 0.f, 0.f);
#pragma unroll
  for (int c = 0; c < 4; ++c)
    if (c < nch) {
      const float4* Oc = (const float4*)(po + (size_t)(base + c) * (64 * 128) + row * 128 + cseg);
      const float f = fac[c];
#pragma unroll
      for (int q = 0; q < 8; ++q) {
        const float4 t = Oc[q];
        o[q].x += t.x * f; o[q].y += t.y * f; o[q].z += t.z * f; o[q].w += t.w * f;
      }
    }

  const size_t gidx = ((size_t)(b * S_ + it * 64 + row)) * D_ + h * DH_ + cseg;
  const float4* F = (const float4*)(fb + gidx);
  u16* out = fbh + gidx;
#pragma unroll
  for (int q = 0; q < 8; ++q) {
    const float4 fv = F[q];
    ushort4 u;
    u.x = f2bf(fv.x + o[q].x * inv);
    u.y = f2bf(fv.y + o[q].y * inv);
    u.z = f2bf(fv.z + o[q].z * inv);
    u.w = f2bf(fv.w + o[q].w * inv);
    *(ushort4*)(out + q * 4) = u;
  }
}

extern "C" void kernel_launch(void* const* d_in, const int* in_sizes, int n_in,
                              void* d_out, int out_size, void* d_ws, size_t ws_size,
                              hipStream_t stream) {
  const int*   tok = (const int*)  d_in[0];
  const float* emb = (const float*)d_in[1];
  const float* Wk  = (const float*)d_in[2];
  const float* Wv  = (const float*)d_in[3];
  const float* Ws  = (const float*)d_in[4];
  const float* Wo  = (const float*)d_in[5];
  const float* stp = (const float*)d_in[6];
  const float* nw  = (const float*)d_in[7];
  const float* gam = (const float*)d_in[8];
  const float* bet = (const float*)d_in[9];
  const float* onw = (const float*)d_in[10];
  const float* lmw = (const float*)d_in[11];
  float* out = (float*)d_out;

  uint8_t* wsb = (uint8_t*)d_ws;
  float* x   = (float*)wsb;  wsb += (size_t)ROWS * D_ * 4;        // 8 MB
  u16* hb    = (u16*)wsb;    wsb += (size_t)ROWS * D_ * 2;        // 4 MB
  u16* kb    = (u16*)wsb;    wsb += (size_t)ROWS * D_ * 2;        // 4 MB
  u16* vt    = (u16*)wsb;    wsb += (size_t)ROWS * D_ * 2;        // 4 MB  [b][col][s]
  float* fb  = (float*)wsb;  wsb += (size_t)ROWS * D_ * 4;        // 8 MB
  u16* fbh   = (u16*)wsb;    wsb += (size_t)ROWS * D_ * 2;        // 4 MB
  u16* Wcat  = (u16*)wsb;    wsb += (size_t)3 * D_ * D_ * 2;      // 6 MB [Wk;Wv;Ws]
  u16* Wob   = (u16*)wsb;    wsb += (size_t)D_ * D_ * 2;          // 2 MB
  float* po  = (float*)wsb;  wsb += (size_t)1024 * 64 * 128 * 4;  // 32 MB partial O
  float* pml = (float*)wsb;  wsb += (size_t)1024 * 128 * 4;       // 0.5 MB partial m/l
  u16* Wlm   = (u16*)wsb;    wsb += (size_t)V_ * D_ * 2;          // 103 MB

  const float scale = 0.08838834764831845f;  // 1/sqrt(DH)
  const int n4 = D_ * D_ / 4;

  k_cvt<<<1024, 256, 0, stream>>>(Wk, Wcat, n4);
  k_cvt<<<1024, 256, 0, stream>>>(Wv, Wcat + (size_t)D_ * D_, n4);
  k_cvt<<<1024, 256, 0, stream>>>(Ws, Wcat + (size_t)2 * D_ * D_, n4);
  k_cvt<<<1024, 256, 0, stream>>>(Wo, Wob, n4);
  k_embed<<<ROWS, 256, 0, stream>>>(tok, emb, x);

  for (int it = 0; it < IT_; ++it) {
    k_rmsnorm<<<ROWS, 256, 0, stream>>>(x, nw + (size_t)it * D_,
                                        gam + (size_t)it * D_, bet + (size_t)it * D_, hb);
    k_gemm_qkv<<<768, 256, 0, stream>>>(hb, Wcat, kb, vt, fb);
    k_attn_part<<<dim3(40, 16), 256, 0, stream>>>(kb, vt, po, pml, scale);
    k_attn_merge<<<dim3(16, 16), 256, 0, stream>>>(po, pml, fb, fbh);
    k_gemm2<<<256, 256, 0, stream>>>(fbh, D_, Wob, D_, x, D_, D_, stp, it);
  }

  k_rmsnorm<<<ROWS, 256, 0, stream>>>(x, onw, nullptr, nullptr, hb);

  // lm_head: single full bf16 conversion + single GEMM
  // grid = 16 i-tiles x 393 j-panels = 6288 blocks (divisible by 8 XCDs)
  k_cvt<<<(V_ * 256 + 255) / 256, 256, 0, stream>>>(lmw, Wlm, V_ * D_ / 4);
  k_gemm_lm<<<16 * ((V_ + 127) / 128), 256, 0, stream>>>(hb, D_, Wlm, D_, out, V_, V_, D_);
}

// Round 14
// 2729.580 us; speedup vs baseline: 1.0121x; 1.0121x over previous
//
#include <hip/hip_runtime.h>
#include <cstdint>
#include <cstddef>

#define S_   1024
#define D_   1024
#define H_   8
#define DH_  128
#define IT_  28
#define V_   50257
#define B_   2
#define ROWS 2048
#define EPS_ 1.1920929e-07f

typedef unsigned short u16;
typedef __attribute__((ext_vector_type(8))) short s8v;    // 8 bf16 in 4 VGPRs
typedef __attribute__((ext_vector_type(4))) float f4v;    // MFMA accumulator

#define VMCNT0 asm volatile("s_waitcnt vmcnt(0)" ::: "memory")
#define LGKM0  asm volatile("s_waitcnt lgkmcnt(0)" ::: "memory")
#define RBAR   do { __builtin_amdgcn_s_barrier(); asm volatile("" ::: "memory"); } while (0)

static __device__ __forceinline__ void gload16(const void* g, void* l) {
  __builtin_amdgcn_global_load_lds((__attribute__((address_space(1))) void*)(g),
                                   (__attribute__((address_space(3))) void*)(l), 16, 0, 0);
}

static __device__ __forceinline__ u16 f2bf(float f) {
  union { float f; uint32_t u; } v; v.f = f;
  return (u16)((v.u + 0x7FFFu + ((v.u >> 16) & 1u)) >> 16);
}

static __device__ __forceinline__ float wave_sum(float v) {
#pragma unroll
  for (int o = 32; o > 0; o >>= 1) v += __shfl_xor(v, o, 64);
  return v;
}

// chunk tables: 40 (it, chunk) pairs per bh, longest chunks first
__device__ __constant__ int IT_TAB[40] = {
  15,15,15,15, 14,14,14, 13,13,13, 12,12,12, 11,11,11,
  10,10, 9,9, 8,8, 7,7, 6, 5, 4, 3,
  14,10,6,2, 13,9,5,1, 12,8,4,0};
__device__ __constant__ int CH_TAB[40] = {
  0,1,2,3, 0,1,2, 0,1,2, 0,1,2, 0,1,2,
  0,1, 0,1, 0,1, 0,1, 0, 0, 0, 0,
  3,2,1,0, 3,2,1,0, 3,2,1,0};

// ---------------- embedding gather ----------------
__global__ __launch_bounds__(256) void k_embed(const int* __restrict__ tok,
                                               const float* __restrict__ emb,
                                               float* __restrict__ x) {
  const int row = blockIdx.x;
  const int t = tok[row];
  ((float4*)(x + (size_t)row * D_))[threadIdx.x] =
      ((const float4*)(emb + (size_t)t * D_))[threadIdx.x];
}

// ---------------- fp32 -> bf16 convert ----------------
__global__ __launch_bounds__(256) void k_cvt(const float* __restrict__ w,
                                             u16* __restrict__ o, int n4) {
  const int idx = blockIdx.x * 256 + threadIdx.x;
  if (idx < n4) {
    const float4 f = ((const float4*)w)[idx];
    ushort4 u;
    u.x = f2bf(f.x); u.y = f2bf(f.y); u.z = f2bf(f.z); u.w = f2bf(f.w);
    ((ushort4*)o)[idx] = u;
  }
}

// ---------------- fused RMSNorm (*nw) [*gamma + beta] -> bf16 ----------------
__global__ __launch_bounds__(256) void k_rmsnorm(const float* __restrict__ x,
                                                 const float* __restrict__ nw,
                                                 const float* __restrict__ g,
                                                 const float* __restrict__ bb,
                                                 u16* __restrict__ h) {
  const int row = blockIdx.x;
  const int tid = threadIdx.x;
  const float4 xv = ((const float4*)(x + (size_t)row * D_))[tid];
  float ss = xv.x*xv.x + xv.y*xv.y + xv.z*xv.z + xv.w*xv.w;
  ss = wave_sum(ss);
  __shared__ float red[4];
  const int lane = tid & 63, wid = tid >> 6;
  if (lane == 0) red[wid] = ss;
  __syncthreads();
  const float tot = red[0] + red[1] + red[2] + red[3];
  const float r = rsqrtf(tot * (1.0f / (float)D_) + EPS_);
  const float4 wv = ((const float4*)nw)[tid];
  float o[4];
  o[0] = xv.x * r * wv.x; o[1] = xv.y * r * wv.y;
  o[2] = xv.z * r * wv.z; o[3] = xv.w * r * wv.w;
  if (g) {
    const float4 gv = ((const float4*)g)[tid];
    const float4 bv = ((const float4*)bb)[tid];
    o[0] = o[0]*gv.x + bv.x; o[1] = o[1]*gv.y + bv.y;
    o[2] = o[2]*gv.z + bv.z; o[3] = o[3]*gv.w + bv.w;
  }
  ushort4 u;
  u.x = f2bf(o[0]); u.y = f2bf(o[1]); u.z = f2bf(o[2]); u.w = f2bf(o[3]);
  ((ushort4*)(h + (size_t)row * D_))[tid] = u;
}

// T2 slot swizzle (all GEMMs): element (row, ks16B) lives at LDS 16B-slot
// row*4 + (ks ^ ((row>>1)&3)).  Staging: pre-swizzled GLOBAL source (within-quad
// permutation of the same 64B line — coalescing intact), LDS dest lane-linear.
// Read: slot = l4 ^ ((l15>>1)&3) -> conflict-free (verified: 25.8M -> 0).
//
// XCD work-clustering: wk=(bid&7)*per+(bid>>3), i-tile fastest -> all i-readers
// of a B-panel on ONE XCD (lm_head FETCH 420->202 MB verified; in-loop -35 us).

// ---------------- in-loop bf16 MFMA NT GEMM (2-phase dbuf + T2 + XCD-cluster) --------
// C[i][j] += alpha * sum_k A[i][k]*B[j][k].  BM=128 BN=64 BK=32, 4 waves (2x2).
// 1-D grid 256 = 8 XCD x (16 i x 2 j-panels).
__global__ __launch_bounds__(256) void k_gemm2(const u16* __restrict__ A, int lda,
                                               const u16* __restrict__ Bm, int ldb,
                                               float* __restrict__ C, int ldc,
                                               int K,
                                               const float* __restrict__ alphap, int aidx) {
  __shared__ u16 As0[128 * 32], As1[128 * 32];
  __shared__ u16 Bs0[64 * 32], Bs1[64 * 32];
  const int wk = (blockIdx.x & 7) * (gridDim.x >> 3) + (blockIdx.x >> 3);
  const int i0 = (wk & 15) * 128;
  const int j0 = (wk >> 4) * 64;
  const int tid = threadIdx.x;
  const int lane = tid & 63, w = tid >> 6;
  const int wr = w >> 1, wc = w & 1;
  const int l15 = lane & 15, l4 = lane >> 4;
  const int ar = tid >> 2;
  const int ak = (((tid & 3) ^ ((ar >> 1) & 3)) << 3);   // swizzled global col offset
  const int sw = (l15 >> 1) & 3;                          // read-side slot XOR

  f4v acc[4][2];
#pragma unroll
  for (int m = 0; m < 4; ++m)
#pragma unroll
    for (int n = 0; n < 2; ++n) acc[m][n] = (f4v)0.0f;

  auto STAGE = [&](u16* AsB, u16* BsB, int k0) {
    gload16(A + (size_t)(i0 + ar) * lda + k0 + ak, AsB + (size_t)tid * 8);
    gload16(A + (size_t)(i0 + ar + 64) * lda + k0 + ak, AsB + ((size_t)tid + 256) * 8);
    gload16(Bm + (size_t)(j0 + ar) * ldb + k0 + ak, BsB + (size_t)tid * 8);
  };
  auto COMP = [&](const u16* AsB, const u16* BsB) {
    s8v a[4], b[2];
#pragma unroll
    for (int m = 0; m < 4; ++m)
      a[m] = *(const s8v*)&AsB[(wr * 64 + m * 16 + l15) * 32 + ((l4 ^ sw) << 3)];
#pragma unroll
    for (int n = 0; n < 2; ++n)
      b[n] = *(const s8v*)&BsB[(wc * 32 + n * 16 + l15) * 32 + ((l4 ^ sw) << 3)];
#pragma unroll
    for (int m = 0; m < 4; ++m)
#pragma unroll
      for (int n = 0; n < 2; ++n)
        acc[m][n] = __builtin_amdgcn_mfma_f32_16x16x32_bf16(a[m], b[n], acc[m][n], 0, 0, 0);
  };

  STAGE(As0, Bs0, 0);
  VMCNT0;
  RBAR;
  for (int k0 = 0; k0 < K; k0 += 64) {
    STAGE(As1, Bs1, k0 + 32);
    COMP(As0, Bs0);
    VMCNT0;
    RBAR;
    if (k0 + 64 < K) STAGE(As0, Bs0, k0 + 64);
    COMP(As1, Bs1);
    VMCNT0;
    RBAR;
  }

  const float alpha = alphap[aidx];
#pragma unroll
  for (int m = 0; m < 4; ++m) {
#pragma unroll
    for (int n = 0; n < 2; ++n) {
      const int i = i0 + wr * 64 + m * 16 + l4 * 4;
      const int j = j0 + wc * 32 + n * 16 + l15;
      const f4v v = acc[m][n];
#pragma unroll
      for (int r = 0; r < 4; ++r) C[(size_t)(i + r) * ldc + j] += alpha * v[r];
    }
  }
}

// ---------------- lm_head GEMM (3-buf counted pipeline + T2 + XCD-clustered work) ----------------
// C[i][j] = sum_k A[i][k]*B[j][k], store f32 guarded j<N.  BM=128 BN=128 BK=32.
__global__ __launch_bounds__(256) void k_gemm_lm(const u16* __restrict__ A, int lda,
                                                 const u16* __restrict__ Bm, int ldb,
                                                 float* __restrict__ C, int ldc,
                                                 int N, int K) {
  __shared__ u16 As0[128 * 32], As1[128 * 32], As2[128 * 32];
  __shared__ u16 Bs0[128 * 32], Bs1[128 * 32], Bs2[128 * 32];
  const int per = gridDim.x >> 3;                 // blocks per XCD (6288/8 = 786)
  const int wk = (blockIdx.x & 7) * per + (blockIdx.x >> 3);
  const int i0 = (wk & 15) * 128;                 // i-tile (16 of them, fastest)
  const int j0 = (wk >> 4) * 128;                 // j-panel
  const int tid = threadIdx.x;
  const int lane = tid & 63, w = tid >> 6;
  const int wr = w >> 1, wc = w & 1;
  const int l15 = lane & 15, l4 = lane >> 4;
  const int ar = tid >> 2;
  const int ak = (((tid & 3) ^ ((ar >> 1) & 3)) << 3);
  const int sw = (l15 >> 1) & 3;
  int bj0 = j0 + ar;      if (bj0 > N - 1) bj0 = N - 1;
  int bj1 = j0 + ar + 64; if (bj1 > N - 1) bj1 = N - 1;

  f4v acc[4][4];
#pragma unroll
  for (int m = 0; m < 4; ++m)
#pragma unroll
    for (int n = 0; n < 4; ++n) acc[m][n] = (f4v)0.0f;

  auto STAGE = [&](u16* AsB, u16* BsB, int k0) {
    gload16(A + (size_t)(i0 + ar) * lda + k0 + ak, AsB + (size_t)tid * 8);
    gload16(A + (size_t)(i0 + ar + 64) * lda + k0 + ak, AsB + ((size_t)tid + 256) * 8);
    gload16(Bm + (size_t)bj0 * ldb + k0 + ak, BsB + (size_t)tid * 8);
    gload16(Bm + (size_t)bj1 * ldb + k0 + ak, BsB + ((size_t)tid + 256) * 8);
  };
  auto COMP = [&](const u16* AsB, const u16* BsB) {
    s8v a[4], b[4];
#pragma unroll
    for (int m = 0; m < 4; ++m)
      a[m] = *(const s8v*)&AsB[(wr * 64 + m * 16 + l15) * 32 + ((l4 ^ sw) << 3)];
#pragma unroll
    for (int n = 0; n < 4; ++n)
      b[n] = *(const s8v*)&BsB[(wc * 64 + n * 16 + l15) * 32 + ((l4 ^ sw) << 3)];
#pragma unroll
    for (int m = 0; m < 4; ++m)
#pragma unroll
      for (int n = 0; n < 4; ++n)
        acc[m][n] = __builtin_amdgcn_mfma_f32_16x16x32_bf16(a[m], b[n], acc[m][n], 0, 0, 0);
  };
  auto WAIT = [&](int ahead) {
    if (ahead >= 2)      asm volatile("s_waitcnt vmcnt(8)" ::: "memory");
    else if (ahead == 1) asm volatile("s_waitcnt vmcnt(4)" ::: "memory");
    else                 VMCNT0;
  };

  const int nk = K >> 5;  // K multiple of 32, nk >= 3
  STAGE(As0, Bs0, 0);
  STAGE(As1, Bs1, 32);
  STAGE(As2, Bs2, 64);
  for (int i = 0; i < nk; ++i) {
    u16 *Asb, *Bsb;
    const int m3 = i % 3;
    if (m3 == 0) { Asb = As0; Bsb = Bs0; }
    else if (m3 == 1) { Asb = As1; Bsb = Bs1; }
    else { Asb = As2; Bsb = Bs2; }
    const int rem = nk - 1 - i;
    WAIT(rem < 2 ? rem : 2);
    RBAR;
    COMP(Asb, Bsb);
    RBAR;
    if (i + 3 < nk) STAGE(Asb, Bsb, (i + 3) << 5);
  }

#pragma unroll
  for (int m = 0; m < 4; ++m) {
#pragma unroll
    for (int n = 0; n < 4; ++n) {
      const int i = i0 + wr * 64 + m * 16 + l4 * 4;
      const int j = j0 + wc * 64 + n * 16 + l15;
      const f4v v = acc[m][n];
      if (j < N) {
#pragma unroll
        for (int r = 0; r < 4; ++r) C[(size_t)(i + r) * ldc + j] = v[r];
      }
    }
  }
}

// ---------------- batched QKV GEMM (2-phase dbuf + T2 + XCD-cluster) ----------------
// A=hb[2048][1024], B=Wcat[3072][1024]; BM=128 BN=64 BK=32.
// 1-D grid 768 = 8 XCD x (16 i x 6 j-panels).
__global__ __launch_bounds__(256) void k_gemm_qkv(const u16* __restrict__ A,
                                                  const u16* __restrict__ Wcat,
                                                  u16* __restrict__ kb,
                                                  u16* __restrict__ vt,
                                                  float* __restrict__ fb) {
  __shared__ u16 As0[128 * 32], As1[128 * 32];
  __shared__ u16 Bs0[64 * 32], Bs1[64 * 32];
  const int wk = (blockIdx.x & 7) * (gridDim.x >> 3) + (blockIdx.x >> 3);
  const int i0 = (wk & 15) * 128;
  const int j0 = (wk >> 4) * 64;
  const int tid = threadIdx.x;
  const int lane = tid & 63, w = tid >> 6;
  const int wr = w >> 1, wc = w & 1;
  const int l15 = lane & 15, l4 = lane >> 4;
  const int ar = tid >> 2;
  const int ak = (((tid & 3) ^ ((ar >> 1) & 3)) << 3);
  const int sw = (l15 >> 1) & 3;

  f4v acc[4][2];
#pragma unroll
  for (int m = 0; m < 4; ++m)
#pragma unroll
    for (int n = 0; n < 2; ++n) acc[m][n] = (f4v)0.0f;

  auto STAGE = [&](u16* AsB, u16* BsB, int k0) {
    gload16(A + (size_t)(i0 + ar) * D_ + k0 + ak, AsB + (size_t)tid * 8);
    gload16(A + (size_t)(i0 + ar + 64) * D_ + k0 + ak, AsB + ((size_t)tid + 256) * 8);
    gload16(Wcat + (size_t)(j0 + ar) * D_ + k0 + ak, BsB + (size_t)tid * 8);
  };
  auto COMP = [&](const u16* AsB, const u16* BsB) {
    s8v a[4], b[2];
#pragma unroll
    for (int m = 0; m < 4; ++m)
      a[m] = *(const s8v*)&AsB[(wr * 64 + m * 16 + l15) * 32 + ((l4 ^ sw) << 3)];
#pragma unroll
    for (int n = 0; n < 2; ++n)
      b[n] = *(const s8v*)&BsB[(wc * 32 + n * 16 + l15) * 32 + ((l4 ^ sw) << 3)];
#pragma unroll
    for (int m = 0; m < 4; ++m)
#pragma unroll
      for (int n = 0; n < 2; ++n)
        acc[m][n] = __builtin_amdgcn_mfma_f32_16x16x32_bf16(a[m], b[n], acc[m][n], 0, 0, 0);
  };

  STAGE(As0, Bs0, 0);
  VMCNT0;
  RBAR;
  for (int k0 = 0; k0 < D_; k0 += 64) {
    STAGE(As1, Bs1, k0 + 32);
    COMP(As0, Bs0);
    VMCNT0;
    RBAR;
    if (k0 + 64 < D_) STAGE(As0, Bs0, k0 + 64);
    COMP(As1, Bs1);
    VMCNT0;
    RBAR;
  }

#pragma unroll
  for (int m = 0; m < 4; ++m) {
#pragma unroll
    for (int n = 0; n < 2; ++n) {
      const int i = i0 + wr * 64 + m * 16 + l4 * 4;
      const int j = j0 + wc * 32 + n * 16 + l15;
      const int sel = j >> 10, jl = j & 1023;
      const f4v v = acc[m][n];
      if (sel == 0) {
#pragma unroll
        for (int r = 0; r < 4; ++r) kb[(size_t)(i + r) * D_ + jl] = f2bf(v[r]);
      } else if (sel == 1) {
        ushort4 p;
        p.x = f2bf(v[0]); p.y = f2bf(v[1]); p.z = f2bf(v[2]); p.w = f2bf(v[3]);
        *(ushort4*)&vt[((size_t)(i >> 10) * D_ + jl) * S_ + (i & 1023)] = p;
      } else {
#pragma unroll
        for (int r = 0; r < 4; ++r) fb[(size_t)(i + r) * D_ + jl] = v[r];
      }
    }
  }
}

// ---------------- flash attention partial: one (it, j-chunk<=4 tiles) per block ----------------
// Round 14: single-buffer staging (4 blocks/CU restored — round-13 dbuf cost
// occupancy and regressed), 2 barriers/tile: the P->LDS barrier is replaced by
// LGKM0 + sched_barrier(0) since Pl[w] is strictly wave-private (rule #18 fence).
__global__ __launch_bounds__(256) void k_attn_part(const u16* __restrict__ kb,
                                                   const u16* __restrict__ vt,
                                                   float* __restrict__ po,
                                                   float* __restrict__ pml,
                                                   float scale) {
  const int it = IT_TAB[blockIdx.x], ch = CH_TAB[blockIdx.x];
  const int z = blockIdx.y;
  const int b = z >> 3, h = z & 7;
  const u16* Kbh = kb + (size_t)b * S_ * D_ + h * DH_;      // row s, stride D_
  const u16* Vth = vt + ((size_t)b * D_ + h * DH_) * S_;    // row d, stride S_
  const int i0 = it * 64;
  const int jt0 = ch * 4;
  const int jtend = min(jt0 + 4, it + 1);
  __shared__ u16 Kj[64 * 128];   // [j-row][k] swizzled
  __shared__ u16 Vj[128 * 64];   // [d][j] swizzled
  __shared__ u16 Pl[4][16 * 64]; // per-wave P, swizzled
  const int tid = threadIdx.x;
  const int lane = tid & 63, w = tid >> 6;
  const int l15 = lane & 15, l4 = lane >> 4;

  s8v ka[4];
#pragma unroll
  for (int ks = 0; ks < 4; ++ks)
    ka[ks] = *(const s8v*)(Kbh + (size_t)(i0 + w * 16 + l15) * D_ + ks * 32 + l4 * 8);

  f4v acc_o[8];
#pragma unroll
  for (int n = 0; n < 8; ++n) acc_o[n] = (f4v)0.0f;
  float mrow[4], lrow[4];
#pragma unroll
  for (int r = 0; r < 4; ++r) { mrow[r] = -3.0e38f; lrow[r] = 0.f; }

  const int krow = tid >> 4, koff = (tid & 15) * 8;  // Kj staging
  const int vrow = tid >> 3, voff = (tid & 7) * 8;   // Vj staging

  for (int jt = jt0; jt < jtend; ++jt) {
    const int j0 = jt * 64;
#pragma unroll
    for (int p = 0; p < 4; ++p) {
      const int row = p * 16 + krow;
      gload16(Kbh + (size_t)(j0 + row) * D_ + (koff ^ ((row & 7) << 3)),
              &Kj[(size_t)(p * 256 + tid) * 8]);
    }
#pragma unroll
    for (int p = 0; p < 4; ++p) {
      const int row = p * 32 + vrow;
      gload16(Vth + (size_t)row * S_ + j0 + (voff ^ ((row & 7) << 3)),
              &Vj[(size_t)(p * 256 + tid) * 8]);
    }
    __syncthreads();

    // S = K_i . K_j^T
    f4v s[4];
#pragma unroll
    for (int n = 0; n < 4; ++n) s[n] = (f4v)0.0f;
    __builtin_amdgcn_s_setprio(1);
#pragma unroll
    for (int ks = 0; ks < 4; ++ks) {
#pragma unroll
      for (int n = 0; n < 4; ++n) {
        const int row = n * 16 + l15;
        const s8v kf = *(const s8v*)&Kj[row * 128 + ((ks * 32 + l4 * 8) ^ ((row & 7) << 3))];
        s[n] = __builtin_amdgcn_mfma_f32_16x16x32_bf16(ka[ks], kf, s[n], 0, 0, 0);
      }
    }
    __builtin_amdgcn_s_setprio(0);

    // online softmax of logits = -scale*S, causal
    float pv[4][4], tmax[4];
#pragma unroll
    for (int r = 0; r < 4; ++r) tmax[r] = -3.0e38f;
#pragma unroll
    for (int n = 0; n < 4; ++n) {
      const int j = j0 + n * 16 + l15;
#pragma unroll
      for (int r = 0; r < 4; ++r) {
        const int i = i0 + w * 16 + l4 * 4 + r;
        const float lg = (j <= i) ? (-scale * s[n][r]) : -3.0e38f;
        pv[n][r] = lg;
        tmax[r] = fmaxf(tmax[r], lg);
      }
    }
#pragma unroll
    for (int r = 0; r < 4; ++r) {
#pragma unroll
      for (int o = 8; o > 0; o >>= 1) tmax[r] = fmaxf(tmax[r], __shfl_xor(tmax[r], o, 64));
    }
    float es[4];
#pragma unroll
    for (int r = 0; r < 4; ++r) {
      const float mn = fmaxf(mrow[r], tmax[r]);
      es[r] = __expf(mrow[r] - mn);
      mrow[r] = mn;
    }
    float psum[4] = {0.f, 0.f, 0.f, 0.f};
#pragma unroll
    for (int n = 0; n < 4; ++n) {
#pragma unroll
      for (int r = 0; r < 4; ++r) {
        const float p = __expf(pv[n][r] - mrow[r]);
        pv[n][r] = p;
        psum[r] += p;
      }
    }
#pragma unroll
    for (int r = 0; r < 4; ++r) {
#pragma unroll
      for (int o = 8; o > 0; o >>= 1) psum[r] += __shfl_xor(psum[r], o, 64);
      lrow[r] = lrow[r] * es[r] + psum[r];
    }
#pragma unroll
    for (int n = 0; n < 8; ++n) {
      f4v t = acc_o[n];
      t[0] *= es[0]; t[1] *= es[1]; t[2] *= es[2]; t[3] *= es[3];
      acc_o[n] = t;
    }

    // P -> per-wave LDS (swizzled); wave-private, so lgkmcnt ordering suffices
    u16* P = Pl[w];
#pragma unroll
    for (int n = 0; n < 4; ++n) {
#pragma unroll
      for (int r = 0; r < 4; ++r) {
        const int row = l4 * 4 + r;
        P[row * 64 + ((n * 16 + l15) ^ ((row & 7) << 3))] = f2bf(pv[n][r]);
      }
    }
    LGKM0;
    __builtin_amdgcn_sched_barrier(0);
    s8v pa[2];
#pragma unroll
    for (int kp = 0; kp < 2; ++kp)
      pa[kp] = *(const s8v*)&P[l15 * 64 + ((kp * 32 + l4 * 8) ^ ((l15 & 7) << 3))];

    // O += P . V
    __builtin_amdgcn_s_setprio(1);
#pragma unroll
    for (int kp = 0; kp < 2; ++kp) {
#pragma unroll
      for (int n = 0; n < 8; ++n) {
        const int d = n * 16 + l15;
        const s8v vf = *(const s8v*)&Vj[d * 64 + ((kp * 32 + l4 * 8) ^ ((d & 7) << 3))];
        acc_o[n] = __builtin_amdgcn_mfma_f32_16x16x32_bf16(pa[kp], vf, acc_o[n], 0, 0, 0);
      }
    }
    __builtin_amdgcn_s_setprio(0);
    __syncthreads();   // all waves done reading Kj/Vj before next tile's staging
  }

  // partial store: O (unnormalized), m, l
  const int slot = (z * 16 + it) * 4 + ch;
  float* O = po + (size_t)slot * (64 * 128);
#pragma unroll
  for (int n = 0; n < 8; ++n) {
#pragma unroll
    for (int r = 0; r < 4; ++r)
      O[(w * 16 + l4 * 4 + r) * 128 + n * 16 + l15] = acc_o[n][r];
  }
  if (l15 == 0) {
#pragma unroll
    for (int r = 0; r < 4; ++r) {
      const int row = w * 16 + l4 * 4 + r;
      pml[(size_t)slot * 128 + row] = mrow[r];
      pml[(size_t)slot * 128 + 64 + row] = lrow[r];
    }
  }
}

// ---------------- merge partial attention chunks; fbh = bf16(fb + O/l) ----------------
__global__ __launch_bounds__(256) void k_attn_merge(const float* __restrict__ po,
                                                    const float* __restrict__ pml,
                                                    const float* __restrict__ fb,
                                                    u16* __restrict__ fbh) {
  const int it = blockIdx.x, z = blockIdx.y;
  const int b = z >> 3, h = z & 7;
  const int nch = (it >> 2) + 1;
  const int row = threadIdx.x >> 2;            // 0..63
  const int cseg = (threadIdx.x & 3) * 32;     // col base within 128
  const int base = (z * 16 + it) * 4;

  float ms = -3.0e38f, mv[4], lv[4];
#pragma unroll
  for (int c = 0; c < 4; ++c)
    if (c < nch) {
      mv[c] = pml[(size_t)(base + c) * 128 + row];
      lv[c] = pml[(size_t)(base + c) * 128 + 64 + row];
      ms = fmaxf(ms, mv[c]);
    }
  float ls = 0.f, fac[4];
#pragma unroll
  for (int c = 0; c < 4; ++c)
    if (c < nch) { fac[c] = __expf(mv[c] - ms); ls += lv[c] * fac[c]; }
  const float inv = 1.0f / ls;

  float4 o[8];
#pragma unroll
  for (int q = 0; q < 8; ++q) o[q] = make_float4(0.f, 0.f, 0.f, 0.f);
#pragma unroll
  for (int c = 0; c < 4; ++c)
    if (c < nch) {
      const float4* Oc = (const float4*)(po + (size_t)(base + c) * (64 * 128) + row * 128 + cseg);
      const float f = fac[c];
#pragma unroll
      for (int q = 0; q < 8; ++q) {
        const float4 t = Oc[q];
        o[q].x += t.x * f; o[q].y += t.y * f; o[q].z += t.z * f; o[q].w += t.w * f;
      }
    }

  const size_t gidx = ((size_t)(b * S_ + it * 64 + row)) * D_ + h * DH_ + cseg;
  const float4* F = (const float4*)(fb + gidx);
  u16* out = fbh + gidx;
#pragma unroll
  for (int q = 0; q < 8; ++q) {
    const float4 fv = F[q];
    ushort4 u;
    u.x = f2bf(fv.x + o[q].x * inv);
    u.y = f2bf(fv.y + o[q].y * inv);
    u.z = f2bf(fv.z + o[q].z * inv);
    u.w = f2bf(fv.w + o[q].w * inv);
    *(ushort4*)(out + q * 4) = u;
  }
}

extern "C" void kernel_launch(void* const* d_in, const int* in_sizes, int n_in,
                              void* d_out, int out_size, void* d_ws, size_t ws_size,
                              hipStream_t stream) {
  const int*   tok = (const int*)  d_in[0];
  const float* emb = (const float*)d_in[1];
  const float* Wk  = (const float*)d_in[2];
  const float* Wv  = (const float*)d_in[3];
  const float* Ws  = (const float*)d_in[4];
  const float* Wo  = (const float*)d_in[5];
  const float* stp = (const float*)d_in[6];
  const float* nw  = (const float*)d_in[7];
  const float* gam = (const float*)d_in[8];
  const float* bet = (const float*)d_in[9];
  const float* onw = (const float*)d_in[10];
  const float* lmw = (const float*)d_in[11];
  float* out = (float*)d_out;

  uint8_t* wsb = (uint8_t*)d_ws;
  float* x   = (float*)wsb;  wsb += (size_t)ROWS * D_ * 4;        // 8 MB
  u16* hb    = (u16*)wsb;    wsb += (size_t)ROWS * D_ * 2;        // 4 MB
  u16* kb    = (u16*)wsb;    wsb += (size_t)ROWS * D_ * 2;        // 4 MB
  u16* vt    = (u16*)wsb;    wsb += (size_t)ROWS * D_ * 2;        // 4 MB  [b][col][s]
  float* fb  = (float*)wsb;  wsb += (size_t)ROWS * D_ * 4;        // 8 MB
  u16* fbh   = (u16*)wsb;    wsb += (size_t)ROWS * D_ * 2;        // 4 MB
  u16* Wcat  = (u16*)wsb;    wsb += (size_t)3 * D_ * D_ * 2;      // 6 MB [Wk;Wv;Ws]
  u16* Wob   = (u16*)wsb;    wsb += (size_t)D_ * D_ * 2;          // 2 MB
  float* po  = (float*)wsb;  wsb += (size_t)1024 * 64 * 128 * 4;  // 32 MB partial O
  float* pml = (float*)wsb;  wsb += (size_t)1024 * 128 * 4;       // 0.5 MB partial m/l
  u16* Wlm   = (u16*)wsb;    wsb += (size_t)V_ * D_ * 2;          // 103 MB

  const float scale = 0.08838834764831845f;  // 1/sqrt(DH)
  const int n4 = D_ * D_ / 4;

  k_cvt<<<1024, 256, 0, stream>>>(Wk, Wcat, n4);
  k_cvt<<<1024, 256, 0, stream>>>(Wv, Wcat + (size_t)D_ * D_, n4);
  k_cvt<<<1024, 256, 0, stream>>>(Ws, Wcat + (size_t)2 * D_ * D_, n4);
  k_cvt<<<1024, 256, 0, stream>>>(Wo, Wob, n4);
  k_embed<<<ROWS, 256, 0, stream>>>(tok, emb, x);

  for (int it = 0; it < IT_; ++it) {
    k_rmsnorm<<<ROWS, 256, 0, stream>>>(x, nw + (size_t)it * D_,
                                        gam + (size_t)it * D_, bet + (size_t)it * D_, hb);
    k_gemm_qkv<<<768, 256, 0, stream>>>(hb, Wcat, kb, vt, fb);
    k_attn_part<<<dim3(40, 16), 256, 0, stream>>>(kb, vt, po, pml, scale);
    k_attn_merge<<<dim3(16, 16), 256, 0, stream>>>(po, pml, fb, fbh);
    k_gemm2<<<256, 256, 0, stream>>>(fbh, D_, Wob, D_, x, D_, D_, stp, it);
  }

  k_rmsnorm<<<ROWS, 256, 0, stream>>>(x, onw, nullptr, nullptr, hb);

  // lm_head: single full bf16 conversion + single GEMM
  // grid = 16 i-tiles x 393 j-panels = 6288 blocks (divisible by 8 XCDs)
  k_cvt<<<(V_ * 256 + 255) / 256, 256, 0, stream>>>(lmw, Wlm, V_ * D_ / 4);
  k_gemm_lm<<<16 * ((V_ + 127) / 128), 256, 0, stream>>>(hb, D_, Wlm, D_, out, V_, V_, D_);
}